// Round 17
// baseline (211.329 us; speedup 1.0000x reference)
//
#include <hip/hip_runtime.h>
#include <math.h>

#define N_FILT   80
#define FILT_DIM 251
#define KPAD     256
#define SIG_LEN  32000
#define OUT_LEN  31750
#define BATCH    32
#define TPB      320       // 5 waves: wave w owns filter-block fb = w

#define STRIP    1024      // t-range per block
#define NREP     8         // shifted replicas -> every window is 16B aligned
#define LROW     644       // dwords per replica: %4==0 (16B align), /4 odd (bank spread)
#define OBS2     36        // ob row stride (dwords) for 32-col flush groups

#define TWO_PI_F 6.28318530717958647692f

typedef __attribute__((ext_vector_type(8))) short    short8;   // raw 16B frag
typedef __attribute__((ext_vector_type(8))) _Float16 half8;    // fp16 A/B frag
typedef __attribute__((ext_vector_type(4))) float    float4v;  // C/D frag
typedef __attribute__((ext_vector_type(2))) float    float2v;  // store pair

// ---------------------------------------------------------------------------
// Kernel 1: build 80 sinc band-pass filters directly in fp16.
// ---------------------------------------------------------------------------
__global__ __launch_bounds__(256) void build_filters_kernel(
    const float* __restrict__ b1, const float* __restrict__ band,
    unsigned short* __restrict__ fh)
{
    const int f = blockIdx.x;
    const int i = threadIdx.x;

    const float MINF = 50.0f / 16000.0f;
    const float fb = fabsf(b1[f]) + MINF;
    const float fe = fb + fabsf(band[f]) + MINF;

    float v = 0.0f;
    if (i < FILT_DIM) {
        int m = i - 125; m = (m < 0) ? -m : m;
        if (m == 0) v = 2.0f * fe - 2.0f * fb;
        else {
            float a1 = TWO_PI_F * fb * (float)m;
            float a2 = TWO_PI_F * fe * (float)m;
            v = 2.0f * fe * (sinf(a2) / a2) - 2.0f * fb * (sinf(a1) / a1);
        }
    }

    __shared__ float red[256];
    red[i] = (i < FILT_DIM) ? v : -INFINITY;
    __syncthreads();
    #pragma unroll
    for (int s = 128; s > 0; s >>= 1) {
        if (i < s) red[i] = fmaxf(red[i], red[i + s]);
        __syncthreads();
    }
    const float mx = red[0];

    const float w   = 0.54f - 0.46f * cosf(TWO_PI_F * (float)i / 250.0f);
    const float val = (i < FILT_DIM) ? (v / mx) * w : 0.0f;
    const _Float16 h = (_Float16)val;                 // RNE v_cvt_f16_f32
    fh[f * KPAD + i] = __builtin_bit_cast(unsigned short, h);  // pad rows = 0
}

// ---------------------------------------------------------------------------
// Kernel 2 (R16 DIAGNOSTIC): exact R13 body (proven 85.0 us) with the
// compute+flush loop repeated x3 in one dispatch (idempotent: identical
// values stored thrice).  Purpose: push this dispatch past the ~190 us
// fill kernels into rocprof's top-5 so we finally see FETCH/WRITE/
// MfmaUtil/Occupancy for the REAL workload.  Readout decides between the
// write-allocate-RMW theory (FETCH >= 200 MB/rep -> R18 = aligned ring
// flush) and the fabric-issue-limit theory (FETCH <= 50 MB/rep).
// ---------------------------------------------------------------------------
__global__ __launch_bounds__(TPB, 7) void sinc_mfma_kernel(
    const float* __restrict__ x,
    const unsigned short* __restrict__ fh,
    float* __restrict__ out)
{
    __shared__ __align__(16) unsigned xf[NREP * LROW];     // 20.6 KB
    __shared__ __align__(16) float    ob[5][16 * OBS2];    // 11.5 KB

    const int tid = threadIdx.x;
    const unsigned raw = blockIdx.x;
    const unsigned swz = (raw & 7u) * 128u + (raw >> 3);
    const int strip = (int)(swz & 31u);
    const int n     = (int)(swz >> 5);
    const int e0    = strip * STRIP;
    const float* xp = x + (size_t)n * SIG_LEN;

    // ---- stage x: fp16, 8 shifted replicas (once) --------------------------
    for (int d = tid; d < LROW; d += TPB) {
        const int g = e0 + 2 * d;
        float v0, v1, v2;
        if (g + 2 < SIG_LEN) {
            float2 p = *(const float2*)(xp + g);
            v0 = p.x; v1 = p.y; v2 = xp[g + 2];
        } else {
            v0 = (g     < SIG_LEN) ? xp[g]     : 0.0f;
            v1 = (g + 1 < SIG_LEN) ? xp[g + 1] : 0.0f;
            v2 = (g + 2 < SIG_LEN) ? xp[g + 2] : 0.0f;
        }
        const _Float16 h0 = (_Float16)v0, h1 = (_Float16)v1, h2 = (_Float16)v2;
        union { _Float16 h[2]; unsigned u; } pe, po;
        pe.h[0] = h0; pe.h[1] = h1;
        po.h[0] = h1; po.h[1] = h2;
        xf[0 * LROW + d] = pe.u;
        xf[1 * LROW + d] = po.u;
        if (d >= 1) { xf[2 * LROW + d - 1] = pe.u;
                      xf[3 * LROW + d - 1] = po.u; }
        if (d >= 2) { xf[4 * LROW + d - 2] = pe.u;
                      xf[5 * LROW + d - 2] = po.u; }
        if (d >= 3) { xf[6 * LROW + d - 3] = pe.u;
                      xf[7 * LROW + d - 3] = po.u; }
    }

    // ---- A fragments (once) ------------------------------------------------
    const int lane = tid & 63;
    const int w    = tid >> 6;
    const int m    = lane & 15;
    const int q    = lane >> 4;
    short8 Ah[8];
    {
        const unsigned short* ph = fh + (w * 16 + m) * KPAD + q * 8;
        #pragma unroll
        for (int kb = 0; kb < 8; ++kb)
            Ah[kb] = *(const short8*)(ph + kb * 32);
    }
    __syncthreads();                  // the ONLY barrier

    const int r = m & 7;
    const unsigned base = (unsigned)(r * LROW + 4 * (m >> 3) + 4 * q);

    float* const obw  = &ob[w][0];
    const int    cp   = 2 * (lane & 15);
    const int    rr0  = lane >> 4;
    const size_t row0 = ((size_t)n * N_FILT + w * 16) * OUT_LEN;

    // ==== x3 repetition of the full compute+flush pass (diagnostic) =========
    #pragma unroll 1
    for (int rep = 0; rep < 3; ++rep) {
        for (int gp = 0; gp < 32; ++gp) {
            #pragma unroll
            for (int tl = 0; tl < 2; ++tl) {
                const int tt = gp * 2 + tl;
                float4v a0 = {0.f,0.f,0.f,0.f}, a1 = {0.f,0.f,0.f,0.f};
                const unsigned o0 = base + 8u * (unsigned)tt;
                #pragma unroll
                for (int kk = 0; kk < 4; ++kk) {
                    a0 = __builtin_amdgcn_mfma_f32_16x16x32_f16(
                             __builtin_bit_cast(half8, Ah[2*kk]),
                             __builtin_bit_cast(half8, *(const uint4*)(&xf[o0 + 32*kk])),
                             a0, 0, 0, 0);
                    a1 = __builtin_amdgcn_mfma_f32_16x16x32_f16(
                             __builtin_bit_cast(half8, Ah[2*kk+1]),
                             __builtin_bit_cast(half8, *(const uint4*)(&xf[o0 + 32*kk + 16])),
                             a1, 0, 0, 0);
                }
                const int oc = tl * 16 + m;
                #pragma unroll
                for (int rg = 0; rg < 4; ++rg)
                    obw[(q * 4 + rg) * OBS2 + oc] = a0[rg] + a1[rg];
            }

            const int t0 = e0 + gp * 32 + cp;
            if (t0 + 1 < OUT_LEN) {
                #pragma unroll
                for (int j = 0; j < 4; ++j) {
                    const int row = j * 4 + rr0;
                    const float2v v = *(const float2v*)(&obw[row * OBS2 + cp]);
                    *(float2v*)(out + row0 + (size_t)row * OUT_LEN + t0) = v;
                }
            }
        }
        asm volatile("" ::: "memory");   // keep reps ordered / un-elided
    }
}

// ---------------------------------------------------------------------------
extern "C" void kernel_launch(void* const* d_in, const int* in_sizes, int n_in,
                              void* d_out, int out_size, void* d_ws, size_t ws_size,
                              hipStream_t stream)
{
    const float* x    = (const float*)d_in[0];
    const float* b1   = (const float*)d_in[1];
    const float* band = (const float*)d_in[2];
    float* outp = (float*)d_out;

    unsigned short* fh = (unsigned short*)d_ws;          // 80*256*2 B = 40 KB

    build_filters_kernel<<<dim3(N_FILT), dim3(256), 0, stream>>>(b1, band, fh);

    dim3 grid(1024);                                     // (strip, n) swizzled
    sinc_mfma_kernel<<<grid, dim3(TPB), 0, stream>>>(x, fh, outp);
}